// Round 1
// baseline (753.999 us; speedup 1.0000x reference)
//
#include <hip/hip_runtime.h>

#define IN_CH 512

// ---------------- degree count (in-degree on col) ----------------
__global__ void k_deg(const int* __restrict__ col, int* __restrict__ deg,
                      int E, int N) {
    int e = blockIdx.x * blockDim.x + threadIdx.x;
    if (e < E) {
        int d = col[e];
        if ((unsigned)d < (unsigned)N) atomicAdd(&deg[d], 1);
    }
}

// ---------------- dis = rsqrt(deg + 1) ----------------
__global__ void k_dis(const int* __restrict__ deg, float* __restrict__ dis, int N) {
    int n = blockIdx.x * blockDim.x + threadIdx.x;
    if (n < N) dis[n] = rsqrtf((float)deg[n] + 1.0f);
}

// ---------------- single-block exclusive scan -> row_ptr ----------------
__global__ __launch_bounds__(1024) void k_scan(const int* __restrict__ deg,
                                               int* __restrict__ rp, int N) {
    __shared__ int sums[1024];
    int t = threadIdx.x;
    int chunk = (N + 1023) / 1024;
    int start = t * chunk;
    int end = start + chunk; if (end > N) end = N;
    int s = 0;
    for (int i = start; i < end; ++i) s += deg[i];
    sums[t] = s;
    __syncthreads();
    for (int off = 1; off < 1024; off <<= 1) {
        int v = (t >= off) ? sums[t - off] : 0;
        __syncthreads();
        sums[t] += v;
        __syncthreads();
    }
    int run = sums[t] - s;   // exclusive prefix of this chunk
    for (int i = start; i < end; ++i) { rp[i] = run; run += deg[i]; }
    if (t == 0) rp[N] = sums[1023];
}

// ---------------- CSR fill (src id + edge norm) ----------------
__global__ void k_fill(const int* __restrict__ ei, const float* __restrict__ dis,
                       const int* __restrict__ rp, int* __restrict__ cursor,
                       int* __restrict__ csrc, float* __restrict__ cnorm,
                       int E, int N) {
    int e = blockIdx.x * blockDim.x + threadIdx.x;
    if (e < E) {
        int s = ei[e];
        int d = ei[E + e];
        if ((unsigned)s < (unsigned)N && (unsigned)d < (unsigned)N) {
            int pos = atomicAdd(&cursor[d], 1);
            int idx = rp[d] + pos;
            csrc[idx] = s;
            cnorm[idx] = dis[s] * dis[d];
        }
    }
}

// ---------------- fp32 tiled GEMM: C[M,512] = A[M,512] @ B[512,512] ----------------
#define BM 128
#define BN 128
#define BK 32
#define LDSP (BM + 4)

__global__ __launch_bounds__(256) void k_gemm(const float* __restrict__ A,
                                              const float* __restrict__ B,
                                              float* __restrict__ C, int M) {
    __shared__ float As[BK][LDSP];   // transposed: As[k][m]
    __shared__ float Bs[BK][LDSP];   // Bs[k][n]
    const int t = threadIdx.x;
    const int tx = t & 15, ty = t >> 4;
    const int bm = blockIdx.x * BM, bn = blockIdx.y * BN;

    float acc[8][8];
#pragma unroll
    for (int i = 0; i < 8; ++i)
#pragma unroll
        for (int j = 0; j < 8; ++j) acc[i][j] = 0.0f;

    for (int k0 = 0; k0 < 512; k0 += BK) {
        // stage A tile (128 x 32), transposed into As[k][m]
#pragma unroll
        for (int p = 0; p < 4; ++p) {
            int r = (t >> 3) + p * 32;
            int c = (t & 7) * 4;
            int m = bm + r; if (m > M - 1) m = M - 1;
            float4 v = *(const float4*)(A + (size_t)m * 512 + k0 + c);
            As[c + 0][r] = v.x; As[c + 1][r] = v.y;
            As[c + 2][r] = v.z; As[c + 3][r] = v.w;
        }
        // stage B tile (32 x 128)
#pragma unroll
        for (int p = 0; p < 4; ++p) {
            int kk = (t >> 5) + p * 8;
            int nn = (t & 31) * 4;
            *(float4*)(&Bs[kk][nn]) =
                *(const float4*)(B + (size_t)(k0 + kk) * 512 + bn + nn);
        }
        __syncthreads();
#pragma unroll
        for (int kk = 0; kk < BK; ++kk) {
            float a[8], b[8];
            *(float4*)&a[0] = *(const float4*)&As[kk][ty * 8];
            *(float4*)&a[4] = *(const float4*)&As[kk][ty * 8 + 4];
            *(float4*)&b[0] = *(const float4*)&Bs[kk][tx * 8];
            *(float4*)&b[4] = *(const float4*)&Bs[kk][tx * 8 + 4];
#pragma unroll
            for (int i = 0; i < 8; ++i)
#pragma unroll
                for (int j = 0; j < 8; ++j)
                    acc[i][j] += a[i] * b[j];
        }
        __syncthreads();
    }
#pragma unroll
    for (int i = 0; i < 8; ++i) {
        int m = bm + ty * 8 + i;
        if (m < M) {
            float4 v0 = make_float4(acc[i][0], acc[i][1], acc[i][2], acc[i][3]);
            float4 v1 = make_float4(acc[i][4], acc[i][5], acc[i][6], acc[i][7]);
            *(float4*)(C + (size_t)m * 512 + bn + tx * 8) = v0;
            *(float4*)(C + (size_t)m * 512 + bn + tx * 8 + 4) = v1;
        }
    }
}

// ---------------- layer-1 aggregation fused with bias+ReLU+dot(W2) ----------------
// one block (256 thr) per node; each thread owns 2 features (float2).
// h is never materialized: we emit xw2[n] = relu(agg + b1) . W2 directly.
__global__ __launch_bounds__(256) void k_agg(const float* __restrict__ xw1,
                                             const float* __restrict__ dis,
                                             const int* __restrict__ rp,
                                             const int* __restrict__ csrc,
                                             const float* __restrict__ cnorm,
                                             const float* __restrict__ b1,
                                             const float* __restrict__ W2,
                                             float* __restrict__ xw2) {
    const int n = blockIdx.x;
    const int t = threadIdx.x;
    const float2* base = (const float2*)xw1;   // row stride = 256 float2
    float d = dis[n];
    float2 self = base[(size_t)n * 256 + t];
    float ax = d * d * self.x;
    float ay = d * d * self.y;
    int j = rp[n], jend = rp[n + 1];
    for (; j + 2 <= jend; j += 2) {
        int s0 = csrc[j], s1 = csrc[j + 1];
        float w0 = cnorm[j], w1 = cnorm[j + 1];
        float2 v0 = base[(size_t)s0 * 256 + t];
        float2 v1 = base[(size_t)s1 * 256 + t];
        ax += w0 * v0.x + w1 * v1.x;
        ay += w0 * v0.y + w1 * v1.y;
    }
    if (j < jend) {
        int s0 = csrc[j];
        float w0 = cnorm[j];
        float2 v0 = base[(size_t)s0 * 256 + t];
        ax += w0 * v0.x;
        ay += w0 * v0.y;
    }
    float2 bb = ((const float2*)b1)[t];
    ax = fmaxf(ax + bb.x, 0.0f);
    ay = fmaxf(ay + bb.y, 0.0f);
    float2 w2 = ((const float2*)W2)[t];
    float p = ax * w2.x + ay * w2.y;
#pragma unroll
    for (int off = 32; off > 0; off >>= 1) p += __shfl_down(p, off);
    __shared__ float ws[4];
    if ((t & 63) == 0) ws[t >> 6] = p;
    __syncthreads();
    if (t == 0) xw2[n] = ws[0] + ws[1] + ws[2] + ws[3];
}

// ---------------- layer-2 aggregation on scalars ----------------
__global__ void k_out(const float* __restrict__ xw2, const float* __restrict__ dis,
                      const int* __restrict__ rp, const int* __restrict__ csrc,
                      const float* __restrict__ cnorm, const float* __restrict__ b2,
                      float* __restrict__ out, int N) {
    int n = blockIdx.x * blockDim.x + threadIdx.x;
    if (n >= N) return;
    float d = dis[n];
    float acc = d * d * xw2[n];
    int jend = rp[n + 1];
    for (int j = rp[n]; j < jend; ++j) acc += cnorm[j] * xw2[csrc[j]];
    out[n] = acc + b2[0];
}

extern "C" void kernel_launch(void* const* d_in, const int* in_sizes, int n_in,
                              void* d_out, int out_size, void* d_ws, size_t ws_size,
                              hipStream_t stream) {
    const float* x  = (const float*)d_in[0];
    const int*   ei = (const int*)d_in[1];
    const float* W1 = (const float*)d_in[2];
    const float* b1 = (const float*)d_in[3];
    const float* W2 = (const float*)d_in[4];
    const float* b2 = (const float*)d_in[5];
    float* out = (float*)d_out;

    const int N = in_sizes[0] / IN_CH;   // 50000
    const int E = in_sizes[1] / 2;       // 800000

    char* ws = (char*)d_ws;
    size_t off = 0;
    auto alloc = [&](size_t bytes) {
        char* p = ws + off;
        off += (bytes + 255) & ~(size_t)255;
        return p;
    };
    float* xw1    = (float*)alloc((size_t)N * IN_CH * sizeof(float)); // 102.4 MB
    int*   deg    = (int*)alloc((size_t)N * sizeof(int));
    float* dis    = (float*)alloc((size_t)N * sizeof(float));
    int*   rp     = (int*)alloc((size_t)(N + 1) * sizeof(int));
    int*   cursor = (int*)alloc((size_t)N * sizeof(int));
    int*   csrc   = (int*)alloc((size_t)E * sizeof(int));
    float* cnorm  = (float*)alloc((size_t)E * sizeof(float));
    float* xw2    = (float*)alloc((size_t)N * sizeof(float));

    hipMemsetAsync(deg, 0, (size_t)N * sizeof(int), stream);
    hipMemsetAsync(cursor, 0, (size_t)N * sizeof(int), stream);

    k_deg<<<(E + 255) / 256, 256, 0, stream>>>(ei + E, deg, E, N);
    k_dis<<<(N + 255) / 256, 256, 0, stream>>>(deg, dis, N);
    k_scan<<<1, 1024, 0, stream>>>(deg, rp, N);
    k_fill<<<(E + 255) / 256, 256, 0, stream>>>(ei, dis, rp, cursor, csrc, cnorm, E, N);
    k_gemm<<<dim3((N + BM - 1) / BM, IN_CH / BN), 256, 0, stream>>>(x, W1, xw1, N);
    k_agg<<<N, 256, 0, stream>>>(xw1, dis, rp, csrc, cnorm, b1, W2, xw2);
    k_out<<<(N + 255) / 256, 256, 0, stream>>>(xw2, dis, rp, csrc, cnorm, b2, out, N);
}

// Round 2
// 424.704 us; speedup vs baseline: 1.7754x; 1.7754x over previous
//
#include <hip/hip_runtime.h>

#define IN_CH 512

typedef _Float16 f16x8 __attribute__((ext_vector_type(8)));
typedef float f32x4 __attribute__((ext_vector_type(4)));

// ---------------- degree count (in-degree on col) ----------------
__global__ void k_deg(const int* __restrict__ col, int* __restrict__ deg,
                      int E, int N) {
    int e = blockIdx.x * blockDim.x + threadIdx.x;
    if (e < E) {
        int d = col[e];
        if ((unsigned)d < (unsigned)N) atomicAdd(&deg[d], 1);
    }
}

// ---------------- dis = rsqrt(deg + 1) ----------------
__global__ void k_dis(const int* __restrict__ deg, float* __restrict__ dis, int N) {
    int n = blockIdx.x * blockDim.x + threadIdx.x;
    if (n < N) dis[n] = rsqrtf((float)deg[n] + 1.0f);
}

// ---------------- single-block exclusive scan -> row_ptr ----------------
__global__ __launch_bounds__(1024) void k_scan(const int* __restrict__ deg,
                                               int* __restrict__ rp, int N) {
    __shared__ int sums[1024];
    int t = threadIdx.x;
    int chunk = (N + 1023) / 1024;
    int start = t * chunk;
    int end = start + chunk; if (end > N) end = N;
    int s = 0;
    for (int i = start; i < end; ++i) s += deg[i];
    sums[t] = s;
    __syncthreads();
    for (int off = 1; off < 1024; off <<= 1) {
        int v = (t >= off) ? sums[t - off] : 0;
        __syncthreads();
        sums[t] += v;
        __syncthreads();
    }
    int run = sums[t] - s;   // exclusive prefix of this chunk
    for (int i = start; i < end; ++i) { rp[i] = run; run += deg[i]; }
    if (t == 0) rp[N] = sums[1023];
}

// ---------------- CSR fill (src id + edge norm) ----------------
__global__ void k_fill(const int* __restrict__ ei, const float* __restrict__ dis,
                       const int* __restrict__ rp, int* __restrict__ cursor,
                       int* __restrict__ csrc, float* __restrict__ cnorm,
                       int E, int N) {
    int e = blockIdx.x * blockDim.x + threadIdx.x;
    if (e < E) {
        int s = ei[e];
        int d = ei[E + e];
        if ((unsigned)s < (unsigned)N && (unsigned)d < (unsigned)N) {
            int pos = atomicAdd(&cursor[d], 1);
            int idx = rp[d] + pos;
            csrc[idx] = s;
            cnorm[idx] = dis[s] * dis[d];
        }
    }
}

// ---------------- fp32 -> fp16 conversion of x, padded to M2 rows ----------------
// 8 elements per thread; valid and total are both multiples of 8.
__global__ void k_cvt_x(const float* __restrict__ x, _Float16* __restrict__ xh,
                        int total, int valid) {
    int i = (blockIdx.x * blockDim.x + threadIdx.x) * 8;
    if (i >= total) return;
    f16x8 o;
    if (i < valid) {
        float4 v0 = *(const float4*)(x + i);
        float4 v1 = *(const float4*)(x + i + 4);
        o[0] = (_Float16)v0.x; o[1] = (_Float16)v0.y;
        o[2] = (_Float16)v0.z; o[3] = (_Float16)v0.w;
        o[4] = (_Float16)v1.x; o[5] = (_Float16)v1.y;
        o[6] = (_Float16)v1.z; o[7] = (_Float16)v1.w;
    } else {
        o = (f16x8)0;
    }
    *(f16x8*)(xh + i) = o;
}

// ---------------- W1 (512x512 fp32) -> W1t (transposed fp16) ----------------
__global__ void k_cvt_w(const float* __restrict__ W1, _Float16* __restrict__ W1t) {
    int o = blockIdx.x * blockDim.x + threadIdx.x;   // 512*512 threads
    int k = o & 511, n = o >> 9;
    W1t[o] = (_Float16)W1[k * 512 + n];              // W1t[n][k] = W1[k][n]
}

// ---------------- fp16 MFMA GEMM: C[M2,512] = A[M2,512] @ W1t^T ----------------
// LDS-free: A and B frags loaded straight from L2/L3.
// Block = 256 thr = 4 waves (2x2); each wave computes a 64x64 tile via
// 4x4 fragments of 16x16, K-stepped by 32 (mfma_f32_16x16x32_f16).
__global__ __launch_bounds__(256) void k_gemm(const _Float16* __restrict__ A,
                                              const _Float16* __restrict__ Bt,
                                              _Float16* __restrict__ C) {
    const int t = threadIdx.x;
    const int lane = t & 63, wave = t >> 6;
    const int wm = wave >> 1, wn = wave & 1;
    const int m0 = blockIdx.x * 128 + wm * 64;
    const int n0 = blockIdx.y * 128 + wn * 64;
    const int r = lane & 15, kg = lane >> 4;

    const f16x8* Ab[4];
    const f16x8* Bb[4];
#pragma unroll
    for (int i = 0; i < 4; ++i)
        Ab[i] = (const f16x8*)(A + (size_t)(m0 + i * 16 + r) * 512 + kg * 8);
#pragma unroll
    for (int j = 0; j < 4; ++j)
        Bb[j] = (const f16x8*)(Bt + (size_t)(n0 + j * 16 + r) * 512 + kg * 8);

    f32x4 acc[4][4];
#pragma unroll
    for (int i = 0; i < 4; ++i)
#pragma unroll
        for (int j = 0; j < 4; ++j) acc[i][j] = (f32x4)0.0f;

#pragma unroll
    for (int ks = 0; ks < 16; ++ks) {       // K = 16 * 32
        f16x8 a[4], b[4];
#pragma unroll
        for (int i = 0; i < 4; ++i) a[i] = Ab[i][ks * 4];
#pragma unroll
        for (int j = 0; j < 4; ++j) b[j] = Bb[j][ks * 4];
#pragma unroll
        for (int i = 0; i < 4; ++i)
#pragma unroll
            for (int j = 0; j < 4; ++j)
                acc[i][j] = __builtin_amdgcn_mfma_f32_16x16x32_f16(a[i], b[j], acc[i][j], 0, 0, 0);
    }

    // C/D layout: col = lane&15, row = (lane>>4)*4 + reg
#pragma unroll
    for (int i = 0; i < 4; ++i)
#pragma unroll
        for (int j = 0; j < 4; ++j)
#pragma unroll
            for (int reg = 0; reg < 4; ++reg) {
                int m = m0 + i * 16 + (lane >> 4) * 4 + reg;
                int n = n0 + j * 16 + (lane & 15);
                C[(size_t)m * 512 + n] = (_Float16)acc[i][j][reg];
            }
}

// ---------------- layer-1 aggregation fused with bias+ReLU+dot(W2) ----------------
// one WAVE per node (4 nodes per 256-block); each lane owns 8 channels (16B row chunk).
__global__ __launch_bounds__(256) void k_agg(const _Float16* __restrict__ xw1,
                                             const float* __restrict__ dis,
                                             const int* __restrict__ rp,
                                             const int* __restrict__ csrc,
                                             const float* __restrict__ cnorm,
                                             const float* __restrict__ b1,
                                             const float* __restrict__ W2,
                                             float* __restrict__ xw2, int N) {
    const int n = blockIdx.x * 4 + (threadIdx.x >> 6);
    if (n >= N) return;
    const int l = threadIdx.x & 63;

    float d = dis[n];
    float dd = d * d;
    f16x8 self = *(const f16x8*)(xw1 + (size_t)n * 512 + l * 8);
    float acc[8];
#pragma unroll
    for (int c = 0; c < 8; ++c) acc[c] = dd * (float)self[c];

    int j = rp[n], jend = rp[n + 1];
    for (; j + 2 <= jend; j += 2) {
        int s0 = csrc[j], s1 = csrc[j + 1];
        float w0 = cnorm[j], w1 = cnorm[j + 1];
        f16x8 v0 = *(const f16x8*)(xw1 + (size_t)s0 * 512 + l * 8);
        f16x8 v1 = *(const f16x8*)(xw1 + (size_t)s1 * 512 + l * 8);
#pragma unroll
        for (int c = 0; c < 8; ++c) acc[c] += w0 * (float)v0[c] + w1 * (float)v1[c];
    }
    if (j < jend) {
        int s0 = csrc[j];
        float w0 = cnorm[j];
        f16x8 v0 = *(const f16x8*)(xw1 + (size_t)s0 * 512 + l * 8);
#pragma unroll
        for (int c = 0; c < 8; ++c) acc[c] += w0 * (float)v0[c];
    }

    float4 bb0 = *(const float4*)(b1 + l * 8);
    float4 bb1 = *(const float4*)(b1 + l * 8 + 4);
    float4 w20 = *(const float4*)(W2 + l * 8);
    float4 w21 = *(const float4*)(W2 + l * 8 + 4);
    float bbv[8] = {bb0.x, bb0.y, bb0.z, bb0.w, bb1.x, bb1.y, bb1.z, bb1.w};
    float w2v[8] = {w20.x, w20.y, w20.z, w20.w, w21.x, w21.y, w21.z, w21.w};
    float p = 0.0f;
#pragma unroll
    for (int c = 0; c < 8; ++c) {
        float h = fmaxf(acc[c] + bbv[c], 0.0f);
        p += h * w2v[c];
    }
#pragma unroll
    for (int off = 32; off > 0; off >>= 1) p += __shfl_down(p, off);
    if (l == 0) xw2[n] = p;
}

// ---------------- layer-2 aggregation on scalars ----------------
__global__ void k_out(const float* __restrict__ xw2, const float* __restrict__ dis,
                      const int* __restrict__ rp, const int* __restrict__ csrc,
                      const float* __restrict__ cnorm, const float* __restrict__ b2,
                      float* __restrict__ out, int N) {
    int n = blockIdx.x * blockDim.x + threadIdx.x;
    if (n >= N) return;
    float d = dis[n];
    float acc = d * d * xw2[n];
    int jend = rp[n + 1];
    for (int j = rp[n]; j < jend; ++j) acc += cnorm[j] * xw2[csrc[j]];
    out[n] = acc + b2[0];
}

extern "C" void kernel_launch(void* const* d_in, const int* in_sizes, int n_in,
                              void* d_out, int out_size, void* d_ws, size_t ws_size,
                              hipStream_t stream) {
    const float* x  = (const float*)d_in[0];
    const int*   ei = (const int*)d_in[1];
    const float* W1 = (const float*)d_in[2];
    const float* b1 = (const float*)d_in[3];
    const float* W2 = (const float*)d_in[4];
    const float* b2 = (const float*)d_in[5];
    float* out = (float*)d_out;

    const int N = in_sizes[0] / IN_CH;            // 50000
    const int E = in_sizes[1] / 2;                // 800000
    const int M2 = ((N + 127) / 128) * 128;       // 50048

    char* ws = (char*)d_ws;
    size_t off = 0;
    auto alloc = [&](size_t bytes) {
        char* p = ws + off;
        off += (bytes + 255) & ~(size_t)255;
        return p;
    };
    _Float16* xh   = (_Float16*)alloc((size_t)M2 * 512 * sizeof(_Float16)); // 51.25 MB
    _Float16* xw1h = (_Float16*)alloc((size_t)M2 * 512 * sizeof(_Float16)); // 51.25 MB
    _Float16* W1t  = (_Float16*)alloc((size_t)512 * 512 * sizeof(_Float16));
    int*   deg    = (int*)alloc((size_t)N * sizeof(int));
    float* dis    = (float*)alloc((size_t)N * sizeof(float));
    int*   rp     = (int*)alloc((size_t)(N + 1) * sizeof(int));
    int*   cursor = (int*)alloc((size_t)N * sizeof(int));
    int*   csrc   = (int*)alloc((size_t)E * sizeof(int));
    float* cnorm  = (float*)alloc((size_t)E * sizeof(float));
    float* xw2    = (float*)alloc((size_t)N * sizeof(float));

    hipMemsetAsync(deg, 0, (size_t)N * sizeof(int), stream);
    hipMemsetAsync(cursor, 0, (size_t)N * sizeof(int), stream);

    k_deg<<<(E + 255) / 256, 256, 0, stream>>>(ei + E, deg, E, N);
    k_dis<<<(N + 255) / 256, 256, 0, stream>>>(deg, dis, N);
    k_scan<<<1, 1024, 0, stream>>>(deg, rp, N);
    k_fill<<<(E + 255) / 256, 256, 0, stream>>>(ei, dis, rp, cursor, csrc, cnorm, E, N);

    int total = M2 * 512, valid = N * 512;
    k_cvt_x<<<(total / 8 + 255) / 256, 256, 0, stream>>>(x, xh, total, valid);
    k_cvt_w<<<(512 * 512) / 256, 256, 0, stream>>>(W1, W1t);
    k_gemm<<<dim3(M2 / 128, 4), 256, 0, stream>>>(xh, W1t, xw1h);
    k_agg<<<(N + 3) / 4, 256, 0, stream>>>(xw1h, dis, rp, csrc, cnorm, b1, W2, xw2, N);
    k_out<<<(N + 255) / 256, 256, 0, stream>>>(xw2, dis, rp, csrc, cnorm, b2, out, N);
}

// Round 3
// 371.011 us; speedup vs baseline: 2.0323x; 1.1447x over previous
//
#include <hip/hip_runtime.h>

#define IN_CH 512

typedef _Float16 f16x8 __attribute__((ext_vector_type(8)));
typedef float f32x4 __attribute__((ext_vector_type(4)));

// async global->LDS, 16B per lane. LDS dest is wave-uniform base + lane*16.
__device__ __forceinline__ void gload_lds16(const void* g, void* l) {
    __builtin_amdgcn_global_load_lds(
        (const __attribute__((address_space(1))) unsigned int*)g,
        (__attribute__((address_space(3))) unsigned int*)l, 16, 0, 0);
}

// ---------------- degree count (in-degree on col) ----------------
__global__ void k_deg(const int* __restrict__ col, int* __restrict__ deg,
                      int E, int N) {
    int e = blockIdx.x * blockDim.x + threadIdx.x;
    if (e < E) {
        int d = col[e];
        if ((unsigned)d < (unsigned)N) atomicAdd(&deg[d], 1);
    }
}

// ---------------- dis = rsqrt(deg + 1) ----------------
__global__ void k_dis(const int* __restrict__ deg, float* __restrict__ dis, int N) {
    int n = blockIdx.x * blockDim.x + threadIdx.x;
    if (n < N) dis[n] = rsqrtf((float)deg[n] + 1.0f);
}

// ---------------- single-block exclusive scan -> row_ptr ----------------
__global__ __launch_bounds__(1024) void k_scan(const int* __restrict__ deg,
                                               int* __restrict__ rp, int N) {
    __shared__ int sums[1024];
    int t = threadIdx.x;
    int chunk = (N + 1023) / 1024;
    int start = t * chunk;
    int end = start + chunk; if (end > N) end = N;
    int s = 0;
    for (int i = start; i < end; ++i) s += deg[i];
    sums[t] = s;
    __syncthreads();
    for (int off = 1; off < 1024; off <<= 1) {
        int v = (t >= off) ? sums[t - off] : 0;
        __syncthreads();
        sums[t] += v;
        __syncthreads();
    }
    int run = sums[t] - s;   // exclusive prefix of this chunk
    for (int i = start; i < end; ++i) { rp[i] = run; run += deg[i]; }
    if (t == 0) rp[N] = sums[1023];
}

// ---------------- CSR fill (src id + edge norm) ----------------
__global__ void k_fill(const int* __restrict__ ei, const float* __restrict__ dis,
                       const int* __restrict__ rp, int* __restrict__ cursor,
                       int* __restrict__ csrc, float* __restrict__ cnorm,
                       int E, int N) {
    int e = blockIdx.x * blockDim.x + threadIdx.x;
    if (e < E) {
        int s = ei[e];
        int d = ei[E + e];
        if ((unsigned)s < (unsigned)N && (unsigned)d < (unsigned)N) {
            int pos = atomicAdd(&cursor[d], 1);
            int idx = rp[d] + pos;
            csrc[idx] = s;
            cnorm[idx] = dis[s] * dis[d];
        }
    }
}

// ---------------- fp32 -> fp16 conversion of x, padded to M2 rows ----------------
__global__ void k_cvt_x(const float* __restrict__ x, _Float16* __restrict__ xh,
                        int total, int valid) {
    int i = (blockIdx.x * blockDim.x + threadIdx.x) * 8;
    if (i >= total) return;
    f16x8 o;
    if (i < valid) {
        float4 v0 = *(const float4*)(x + i);
        float4 v1 = *(const float4*)(x + i + 4);
        o[0] = (_Float16)v0.x; o[1] = (_Float16)v0.y;
        o[2] = (_Float16)v0.z; o[3] = (_Float16)v0.w;
        o[4] = (_Float16)v1.x; o[5] = (_Float16)v1.y;
        o[6] = (_Float16)v1.z; o[7] = (_Float16)v1.w;
    } else {
        o = (f16x8)0;
    }
    *(f16x8*)(xh + i) = o;
}

// ---------------- W1 (512x512 fp32) -> W1t (transposed fp16), LDS tile ----------------
__global__ __launch_bounds__(256) void k_cvt_w(const float* __restrict__ W1,
                                               _Float16* __restrict__ W1t) {
    __shared__ float tile[32][33];
    const int bk = blockIdx.x * 32, bn = blockIdx.y * 32;
    const int tx = threadIdx.x & 31, ty = threadIdx.x >> 5;   // 32 x 8
#pragma unroll
    for (int p = 0; p < 4; ++p)
        tile[ty + p * 8][tx] = W1[(size_t)(bk + ty + p * 8) * 512 + bn + tx];
    __syncthreads();
#pragma unroll
    for (int p = 0; p < 4; ++p)
        W1t[(size_t)(bn + ty + p * 8) * 512 + bk + tx] = (_Float16)tile[tx][ty + p * 8];
}

// ---------------- fp16 MFMA GEMM, LDS-staged (m97 structure) ----------------
// C[M2,512] = A[M2,512] @ Bt^T.  Block = 256 thr = 4 waves (2x2 of 64x64).
// BK=64: A tile 128x64 f16 (16KB) + B tile (16KB), global_load_lds width 16.
__global__ __launch_bounds__(256) void k_gemm(const _Float16* __restrict__ A,
                                              const _Float16* __restrict__ Bt,
                                              _Float16* __restrict__ C) {
    __shared__ __align__(16) _Float16 As[128 * 64];
    __shared__ __align__(16) _Float16 Bs[128 * 64];
    const int t = threadIdx.x;
    const int lane = t & 63, w = t >> 6;
    const int wm = w >> 1, wn = w & 1;
    const int bm = blockIdx.x * 128, bn = blockIdx.y * 128;
    const int r = lane & 15, kg = lane >> 4;
    const int lrow = lane >> 3, lcol = (lane & 7) * 8;   // staging: 8 lanes/row

    f32x4 acc[4][4];
#pragma unroll
    for (int i = 0; i < 4; ++i)
#pragma unroll
        for (int j = 0; j < 4; ++j) acc[i][j] = (f32x4)0.0f;

    for (int k0 = 0; k0 < 512; k0 += 64) {
        // stage A and B tiles: per issue q, wave w covers rows q*32+w*8 .. +7
#pragma unroll
        for (int q = 0; q < 4; ++q) {
            const int row = q * 32 + w * 8 + lrow;
            const int ldsbase = (q * 256 + w * 64) * 8;   // elements
            gload_lds16(A + (size_t)(bm + row) * 512 + k0 + lcol, As + ldsbase);
            gload_lds16(Bt + (size_t)(bn + row) * 512 + k0 + lcol, Bs + ldsbase);
        }
        __syncthreads();
#pragma unroll
        for (int kk = 0; kk < 2; ++kk) {
            f16x8 a[4], b[4];
#pragma unroll
            for (int i = 0; i < 4; ++i)
                a[i] = *(const f16x8*)(As + (wm * 64 + i * 16 + r) * 64 + kk * 32 + kg * 8);
#pragma unroll
            for (int j = 0; j < 4; ++j)
                b[j] = *(const f16x8*)(Bs + (wn * 64 + j * 16 + r) * 64 + kk * 32 + kg * 8);
#pragma unroll
            for (int i = 0; i < 4; ++i)
#pragma unroll
                for (int j = 0; j < 4; ++j)
                    acc[i][j] = __builtin_amdgcn_mfma_f32_16x16x32_f16(a[i], b[j], acc[i][j], 0, 0, 0);
        }
        __syncthreads();
    }

    // C/D layout: col = lane&15, row = (lane>>4)*4 + reg
#pragma unroll
    for (int i = 0; i < 4; ++i)
#pragma unroll
        for (int j = 0; j < 4; ++j)
#pragma unroll
            for (int reg = 0; reg < 4; ++reg) {
                int m = bm + wm * 64 + i * 16 + kg * 4 + reg;
                int n = bn + wn * 64 + j * 16 + r;
                C[(size_t)m * 512 + n] = (_Float16)acc[i][j][reg];
            }
}

// ---------------- layer-1 aggregation fused with bias+ReLU+dot(W2) ----------------
// one WAVE per node; each lane owns 8 channels (16B of the 1KB row).
__global__ __launch_bounds__(256) void k_agg(const _Float16* __restrict__ xw1,
                                             const float* __restrict__ dis,
                                             const int* __restrict__ rp,
                                             const int* __restrict__ csrc,
                                             const float* __restrict__ cnorm,
                                             const float* __restrict__ b1,
                                             const float* __restrict__ W2,
                                             float* __restrict__ xw2, int N) {
    const int n = blockIdx.x * 4 + (threadIdx.x >> 6);
    if (n >= N) return;
    const int l = threadIdx.x & 63;

    float d = dis[n];
    float dd = d * d;
    f16x8 self = *(const f16x8*)(xw1 + (size_t)n * 512 + l * 8);
    float acc[8];
#pragma unroll
    for (int c = 0; c < 8; ++c) acc[c] = dd * (float)self[c];

    int j = rp[n], jend = rp[n + 1];
    for (; j + 4 <= jend; j += 4) {
        int s0 = csrc[j], s1 = csrc[j + 1], s2 = csrc[j + 2], s3 = csrc[j + 3];
        float w0 = cnorm[j], w1 = cnorm[j + 1], w2 = cnorm[j + 2], w3 = cnorm[j + 3];
        f16x8 v0 = *(const f16x8*)(xw1 + (size_t)s0 * 512 + l * 8);
        f16x8 v1 = *(const f16x8*)(xw1 + (size_t)s1 * 512 + l * 8);
        f16x8 v2 = *(const f16x8*)(xw1 + (size_t)s2 * 512 + l * 8);
        f16x8 v3 = *(const f16x8*)(xw1 + (size_t)s3 * 512 + l * 8);
#pragma unroll
        for (int c = 0; c < 8; ++c)
            acc[c] += (w0 * (float)v0[c] + w1 * (float)v1[c]) +
                      (w2 * (float)v2[c] + w3 * (float)v3[c]);
    }
    for (; j < jend; ++j) {
        int s0 = csrc[j];
        float w0 = cnorm[j];
        f16x8 v0 = *(const f16x8*)(xw1 + (size_t)s0 * 512 + l * 8);
#pragma unroll
        for (int c = 0; c < 8; ++c) acc[c] += w0 * (float)v0[c];
    }

    float4 bb0 = *(const float4*)(b1 + l * 8);
    float4 bb1 = *(const float4*)(b1 + l * 8 + 4);
    float4 w20 = *(const float4*)(W2 + l * 8);
    float4 w21 = *(const float4*)(W2 + l * 8 + 4);
    float bbv[8] = {bb0.x, bb0.y, bb0.z, bb0.w, bb1.x, bb1.y, bb1.z, bb1.w};
    float w2v[8] = {w20.x, w20.y, w20.z, w20.w, w21.x, w21.y, w21.z, w21.w};
    float p = 0.0f;
#pragma unroll
    for (int c = 0; c < 8; ++c) {
        float h = fmaxf(acc[c] + bbv[c], 0.0f);
        p += h * w2v[c];
    }
#pragma unroll
    for (int off = 32; off > 0; off >>= 1) p += __shfl_down(p, off);
    if (l == 0) xw2[n] = p;
}

// ---------------- layer-2 aggregation on scalars ----------------
__global__ void k_out(const float* __restrict__ xw2, const float* __restrict__ dis,
                      const int* __restrict__ rp, const int* __restrict__ csrc,
                      const float* __restrict__ cnorm, const float* __restrict__ b2,
                      float* __restrict__ out, int N) {
    int n = blockIdx.x * blockDim.x + threadIdx.x;
    if (n >= N) return;
    float d = dis[n];
    float acc = d * d * xw2[n];
    int jend = rp[n + 1];
    for (int j = rp[n]; j < jend; ++j) acc += cnorm[j] * xw2[csrc[j]];
    out[n] = acc + b2[0];
}

extern "C" void kernel_launch(void* const* d_in, const int* in_sizes, int n_in,
                              void* d_out, int out_size, void* d_ws, size_t ws_size,
                              hipStream_t stream) {
    const float* x  = (const float*)d_in[0];
    const int*   ei = (const int*)d_in[1];
    const float* W1 = (const float*)d_in[2];
    const float* b1 = (const float*)d_in[3];
    const float* W2 = (const float*)d_in[4];
    const float* b2 = (const float*)d_in[5];
    float* out = (float*)d_out;

    const int N = in_sizes[0] / IN_CH;            // 50000
    const int E = in_sizes[1] / 2;                // 800000
    const int M2 = ((N + 127) / 128) * 128;       // 50048

    char* ws = (char*)d_ws;
    size_t off = 0;
    auto alloc = [&](size_t bytes) {
        char* p = ws + off;
        off += (bytes + 255) & ~(size_t)255;
        return p;
    };
    _Float16* xh   = (_Float16*)alloc((size_t)M2 * 512 * sizeof(_Float16)); // 51.25 MB
    _Float16* xw1h = (_Float16*)alloc((size_t)M2 * 512 * sizeof(_Float16)); // 51.25 MB
    _Float16* W1t  = (_Float16*)alloc((size_t)512 * 512 * sizeof(_Float16));
    int*   deg    = (int*)alloc((size_t)N * sizeof(int));
    float* dis    = (float*)alloc((size_t)N * sizeof(float));
    int*   rp     = (int*)alloc((size_t)(N + 1) * sizeof(int));
    int*   cursor = (int*)alloc((size_t)N * sizeof(int));
    int*   csrc   = (int*)alloc((size_t)E * sizeof(int));
    float* cnorm  = (float*)alloc((size_t)E * sizeof(float));
    float* xw2    = (float*)alloc((size_t)N * sizeof(float));

    hipMemsetAsync(deg, 0, (size_t)N * sizeof(int), stream);
    hipMemsetAsync(cursor, 0, (size_t)N * sizeof(int), stream);

    k_deg<<<(E + 255) / 256, 256, 0, stream>>>(ei + E, deg, E, N);
    k_dis<<<(N + 255) / 256, 256, 0, stream>>>(deg, dis, N);
    k_scan<<<1, 1024, 0, stream>>>(deg, rp, N);
    k_fill<<<(E + 255) / 256, 256, 0, stream>>>(ei, dis, rp, cursor, csrc, cnorm, E, N);

    int total = M2 * 512, valid = N * 512;
    k_cvt_x<<<(total / 8 + 255) / 256, 256, 0, stream>>>(x, xh, total, valid);
    k_cvt_w<<<dim3(16, 16), 256, 0, stream>>>(W1, W1t);
    k_gemm<<<dim3(M2 / 128, 4), 256, 0, stream>>>(xh, W1t, xw1h);
    k_agg<<<(N + 3) / 4, 256, 0, stream>>>(xw1h, dis, rp, csrc, cnorm, b1, W2, xw2, N);
    k_out<<<(N + 255) / 256, 256, 0, stream>>>(xw2, dis, rp, csrc, cnorm, b2, out, N);
}